// Round 4
// baseline (1476.436 us; speedup 1.0000x reference)
//
#include <hip/hip_runtime.h>
#include <hip/hip_bf16.h>

// ---------------------------------------------------------------------------
// GraphSAGE 2-layer (max-pool), fp32 in/out. Split-bf16 MFMA GEMMs
// (x = hi + lo, 3 products ah*bh + ah*bl + al*bh, fp32 accumulate),
// ~1e-4 abs error vs fp32 reference. r3: desk-audited resubmit of r2 —
// four straight GPU-acquisition failures, no counters yet; holding the
// design stable so the first successful bench validates exactly one thing.
//
// segment_max trick: all msgs >= 0 (relu * w in [0,1)), so
//  - init neigh to 0 == reference's where(isfinite, segmax(-inf-init), 0)
//  - atomicMax on u32 bit pattern is order-correct for non-negative floats
//  - stale-OK pre-read filters atomics (observed value is a lower bound).
// ---------------------------------------------------------------------------

typedef __bf16 bf16x8 __attribute__((ext_vector_type(8)));
typedef float  f32x4  __attribute__((ext_vector_type(4)));

constexpr int NS1 = 262144, ND1 = 32768, E1C = 524288, ND2 = 4096, E2C = 65536;
constexpr int FK  = 256;   // K dim everywhere
constexpr int LDP = 40;    // LDS row stride in bf16 elems (32 k + 8 pad = 80B)
                           // frag ds_read_b128 at stride 80B -> 2-way bank
                           // aliasing only (free, m136); 80 = 5*16 so 16B-aligned

__device__ __forceinline__ void cvt_store(unsigned short* hi, unsigned short* lo,
                                          int off, float4 v)
{
    float f[4] = {v.x, v.y, v.z, v.w};
    ushort4 hs, ls;
    unsigned short* hp = &hs.x;
    unsigned short* lp = &ls.x;
#pragma unroll
    for (int e = 0; e < 4; ++e) {
        __bf16 h = (__bf16)f[e];                    // RNE
        __bf16 l = (__bf16)(f[e] - (float)h);       // residual, next 8 bits
        hp[e] = __builtin_bit_cast(unsigned short, h);
        lp[e] = __builtin_bit_cast(unsigned short, l);
    }
    *(ushort4*)(hi + off) = hs;
    *(ushort4*)(lo + off) = ls;
}

__device__ __forceinline__ bf16x8 load_frag(const unsigned short* p)
{
    f32x4 t = *(const f32x4*)p;                     // ds_read_b128
    return __builtin_bit_cast(bf16x8, t);
}

// C[M][N] = act(A[M][K] @ W[N][K]^T + b1 [+ A2 @ W2^T + b2])
// 256 threads = 4 waves (2x2), wave tile (BM/2)x(BN/2), 16x16x32 bf16 MFMA.
template<int BM, int BN, bool RELU, bool DUAL>
__global__ __launch_bounds__(256, 2)
void mfma_gemm(const float* __restrict__ A, const float* __restrict__ W,
               const float* __restrict__ b1v,
               const float* __restrict__ A2, const float* __restrict__ W2,
               const float* __restrict__ b2v,
               float* __restrict__ C, int M, int N, int K)
{
    constexpr int RF = BM / 32;   // 16x16 row-frags per wave ((BM/2)/16)
    constexpr int CF = BN / 32;   // 16x16 col-frags per wave ((BN/2)/16)
    static_assert(RF >= 1 && CF >= 1 && BM % 32 == 0 && BN % 32 == 0, "tile");

    __shared__ unsigned short Ah[BM * LDP], Al[BM * LDP];
    __shared__ unsigned short Bh[BN * LDP], Bl[BN * LDP];

    const int tid  = threadIdx.x;
    const int wid  = tid >> 6, lane = tid & 63;
    const int wr   = wid >> 1, wc = wid & 1;
    const int lq   = lane >> 4, lr = lane & 15;
    const int m0   = blockIdx.x * BM;
    const int n0   = blockIdx.y * BN;

    f32x4 acc[RF][CF] = {};

    const int nkt = K / 32;
    const int tkt = DUAL ? 2 * nkt : nkt;

    for (int kt = 0; kt < tkt; ++kt) {
        const float* Ap = A;
        const float* Wp = W;
        int kb = kt * 32;
        if (DUAL && kt >= nkt) { Ap = A2; Wp = W2; kb = (kt - nkt) * 32; }

        // ---- stage + split A tile: BM rows x 32 k (8 float4 chunks/row) ----
#pragma unroll
        for (int i = 0; i < BM / 32; ++i) {
            const int c = tid + i * 256;
            const int row = c >> 3, k0 = (c & 7) * 4;
            const float4 v = *(const float4*)(Ap + (size_t)(m0 + row) * K + kb + k0);
            cvt_store(Ah, Al, row * LDP + k0, v);
        }
        // ---- stage + split W tile: BN rows x 32 k ----
#pragma unroll
        for (int i = 0; i < BN / 32; ++i) {
            const int c = tid + i * 256;
            const int row = c >> 3, k0 = (c & 7) * 4;
            const float4 v = *(const float4*)(Wp + (size_t)(n0 + row) * K + kb + k0);
            cvt_store(Bh, Bl, row * LDP + k0, v);
        }
        __syncthreads();

        // ---- fragments: lane holds row (lr), k = lq*8 .. lq*8+7 ----
        bf16x8 ah[RF], al[RF];
#pragma unroll
        for (int i = 0; i < RF; ++i) {
            const int off = (wr * (BM / 2) + i * 16 + lr) * LDP + lq * 8;
            ah[i] = load_frag(Ah + off);
            al[i] = load_frag(Al + off);
        }
#pragma unroll
        for (int j = 0; j < CF; ++j) {
            const int off = (wc * (BN / 2) + j * 16 + lr) * LDP + lq * 8;
            const bf16x8 bh = load_frag(Bh + off);
            const bf16x8 bl = load_frag(Bl + off);
#pragma unroll
            for (int i = 0; i < RF; ++i) {
                acc[i][j] = __builtin_amdgcn_mfma_f32_16x16x32_bf16(ah[i], bh, acc[i][j], 0, 0, 0);
                acc[i][j] = __builtin_amdgcn_mfma_f32_16x16x32_bf16(ah[i], bl, acc[i][j], 0, 0, 0);
                acc[i][j] = __builtin_amdgcn_mfma_f32_16x16x32_bf16(al[i], bh, acc[i][j], 0, 0, 0);
            }
        }
        __syncthreads();
    }

    // ---- epilogue: C/D layout col=lane&15, row=(lane>>4)*4+reg (m89) ----
#pragma unroll
    for (int j = 0; j < CF; ++j) {
        const int col = n0 + wc * (BN / 2) + j * 16 + lr;
        float bias = b1v[col];
        if constexpr (DUAL) bias += b2v[col];
#pragma unroll
        for (int i = 0; i < RF; ++i) {
            const int rbase = m0 + wr * (BM / 2) + i * 16 + lq * 4;
#pragma unroll
            for (int r = 0; r < 4; ++r) {
                float o = acc[i][j][r] + bias;
                if (RELU) o = fmaxf(o, 0.0f);
                C[(size_t)(rbase + r) * N + col] = o;
            }
        }
    }
}

// One wave per edge; each lane handles 4 consecutive feature columns.
__global__ __launch_bounds__(256)
void edge_max_kernel(const float* __restrict__ pooled,
                     const int* __restrict__ src, const int* __restrict__ dst,
                     const float* __restrict__ w,
                     float* neigh, int E)
{
    const int gid  = blockIdx.x * blockDim.x + threadIdx.x;
    const int e    = gid >> 6;
    const int lane = gid & 63;
    if (e >= E) return;

    const int   s  = src[e];
    const int   d  = dst[e];
    const float ww = w[e];

    const float4 p = *(const float4*)(pooled + (size_t)s * FK + lane * 4);
    const float m0 = p.x * ww, m1 = p.y * ww, m2 = p.z * ww, m3 = p.w * ww;

    float* nrow = neigh + (size_t)d * FK + lane * 4;
    const float4 cur = *(const float4*)nrow;   // stale-OK lower bound
    unsigned int* nu = (unsigned int*)nrow;
    if (m0 > cur.x) atomicMax(nu + 0, __float_as_uint(m0));
    if (m1 > cur.y) atomicMax(nu + 1, __float_as_uint(m1));
    if (m2 > cur.z) atomicMax(nu + 2, __float_as_uint(m2));
    if (m3 > cur.w) atomicMax(nu + 3, __float_as_uint(m3));
}

extern "C" void kernel_launch(void* const* d_in, const int* in_sizes, int n_in,
                              void* d_out, int out_size, void* d_ws, size_t ws_size,
                              hipStream_t stream)
{
    const float* x        = (const float*)d_in[0];
    const int*   src1     = (const int*)d_in[1];
    const int*   dst1     = (const int*)d_in[2];
    const float* w1       = (const float*)d_in[3];
    const int*   src2     = (const int*)d_in[4];
    const int*   dst2     = (const int*)d_in[5];
    const float* w2       = (const float*)d_in[6];
    const float* pool_w1  = (const float*)d_in[7];
    const float* pool_b1  = (const float*)d_in[8];
    const float* self_w1  = (const float*)d_in[9];
    const float* self_b1  = (const float*)d_in[10];
    const float* neigh_w1 = (const float*)d_in[11];
    const float* neigh_b1 = (const float*)d_in[12];
    const float* pool_w2  = (const float*)d_in[13];
    const float* pool_b2  = (const float*)d_in[14];
    const float* self_w2  = (const float*)d_in[15];
    const float* self_b2  = (const float*)d_in[16];
    const float* neigh_w2 = (const float*)d_in[17];
    const float* neigh_b2 = (const float*)d_in[18];

    // workspace: pooled1 [0,268.4M) dies after edge1; then h2 [0,33.5M),
    // pooled2 [33.5M,67M), neigh2 [67M,71.2M). neigh1 at [268.4M,301.9M).
    char* ws = (char*)d_ws;
    float* pooled1 = (float*)ws;
    float* neigh1  = (float*)(ws + (size_t)NS1 * FK * 4);
    float* h2      = (float*)ws;
    float* pooled2 = (float*)(ws + (size_t)ND1 * FK * 4);
    float* neigh2  = (float*)(ws + (size_t)2 * ND1 * FK * 4);
    float* out     = (float*)d_out;

    // L1: pooled1 = relu(x @ pool_w1^T + pool_b1)   [262144 x 256], x read once
    mfma_gemm<128, 256, true, false>
        <<<dim3(NS1 / 128, 1), 256, 0, stream>>>(
            x, pool_w1, pool_b1, nullptr, nullptr, nullptr, pooled1, NS1, FK, FK);

    hipMemsetAsync(neigh1, 0, (size_t)ND1 * FK * 4, stream);

    edge_max_kernel<<<E1C / 4, 256, 0, stream>>>(pooled1, src1, dst1, w1, neigh1, E1C);

    // h2 = relu(x[:32k]@self_w1^T + b + neigh1@neigh_w1^T + b)
    mfma_gemm<128, 256, true, true>
        <<<dim3(ND1 / 128, 1), 256, 0, stream>>>(
            x, self_w1, self_b1, neigh1, neigh_w1, neigh_b1, h2, ND1, FK, FK);

    // L2: pooled2 = relu(h2 @ pool_w2^T + pool_b2)  [32768 x 256]
    mfma_gemm<128, 256, true, false>
        <<<dim3(ND1 / 128, 1), 256, 0, stream>>>(
            h2, pool_w2, pool_b2, nullptr, nullptr, nullptr, pooled2, ND1, FK, FK);

    hipMemsetAsync(neigh2, 0, (size_t)ND2 * FK * 4, stream);

    edge_max_kernel<<<E2C / 4, 256, 0, stream>>>(pooled2, src2, dst2, w2, neigh2, E2C);

    // out = h2[:4096]@self_w2^T + b + neigh2@neigh_w2^T + b   (NO relu), N=128
    mfma_gemm<64, 128, false, true>
        <<<dim3(ND2 / 64, 1), 256, 0, stream>>>(
            h2, self_w2, self_b2, neigh2, neigh_w2, neigh_b2, out, ND2, 128, FK);
}

// Round 6
// 769.287 us; speedup vs baseline: 1.9192x; 1.9192x over previous
//
#include <hip/hip_runtime.h>
#include <hip/hip_bf16.h>

// ---------------------------------------------------------------------------
// GraphSAGE 2-layer (max-pool), fp32 in/out. Split-bf16 MFMA GEMMs
// (x = hi + lo, 3 products, fp32 accumulate). r5 = desk-audited resubmit of
// r4 (GPU acquisition failed; design never measured). vs r2 baseline
// (measured 1476us, edge_max 620us latency/atomic-bound, 23% HBM):
//  1. segment_max via device-built CSR (hist+scan+scatter, ~35us) + pull-mode
//     aggregation (1 wave per dst, register max) — NO atomics, no filter
//     reads, no neigh memset. eids1 (2MB) lives in d_out (dead before final
//     GEMM writes it). Max is order-invariant -> bit-identical result.
//  2. GEMM: register prefetch of K-step t+1's global loads issued before the
//     MFMA phase (r2 exposed full HBM latency every K-step).
// ---------------------------------------------------------------------------

typedef __bf16 bf16x8 __attribute__((ext_vector_type(8)));
typedef float  f32x4  __attribute__((ext_vector_type(4)));

constexpr int NS1 = 262144, ND1 = 32768, E1C = 524288, ND2 = 4096, E2C = 65536;
constexpr int FK  = 256;   // K dim everywhere
constexpr int LDP = 40;    // LDS row stride in bf16 elems (32 k + 8 pad = 80B)

__device__ __forceinline__ void cvt_store(unsigned short* hi, unsigned short* lo,
                                          int off, float4 v)
{
    float f[4] = {v.x, v.y, v.z, v.w};
    ushort4 hs, ls;
    unsigned short* hp = &hs.x;
    unsigned short* lp = &ls.x;
#pragma unroll
    for (int e = 0; e < 4; ++e) {
        __bf16 h = (__bf16)f[e];                    // RNE
        __bf16 l = (__bf16)(f[e] - (float)h);       // residual
        hp[e] = __builtin_bit_cast(unsigned short, h);
        lp[e] = __builtin_bit_cast(unsigned short, l);
    }
    *(ushort4*)(hi + off) = hs;
    *(ushort4*)(lo + off) = ls;
}

__device__ __forceinline__ bf16x8 load_frag(const unsigned short* p)
{
    f32x4 t = *(const f32x4*)p;                     // ds_read_b128
    return __builtin_bit_cast(bf16x8, t);
}

// C[M][N] = act(A[M][K] @ W[N][K]^T + b1 [+ A2 @ W2^T + b2])
// 256 threads = 4 waves (2x2), wave tile (BM/2)x(BN/2), 16x16x32 bf16 MFMA.
template<int BM, int BN, bool RELU, bool DUAL>
__global__ __launch_bounds__(256, 2)
void mfma_gemm(const float* __restrict__ A, const float* __restrict__ W,
               const float* __restrict__ b1v,
               const float* __restrict__ A2, const float* __restrict__ W2,
               const float* __restrict__ b2v,
               float* __restrict__ C, int M, int N, int K)
{
    constexpr int RF  = BM / 32;
    constexpr int CF  = BN / 32;
    constexpr int AF4 = BM / 32;   // float4 global loads per thread for A tile
    constexpr int BF4 = BN / 32;   // ... for W tile
    static_assert(RF >= 1 && CF >= 1 && BM % 32 == 0 && BN % 32 == 0, "tile");

    __shared__ unsigned short Ah[BM * LDP], Al[BM * LDP];
    __shared__ unsigned short Bh[BN * LDP], Bl[BN * LDP];

    const int tid  = threadIdx.x;
    const int wid  = tid >> 6, lane = tid & 63;
    const int wr   = wid >> 1, wc = wid & 1;
    const int lq   = lane >> 4, lr = lane & 15;
    const int m0   = blockIdx.x * BM;
    const int n0   = blockIdx.y * BN;

    f32x4 acc[RF][CF] = {};

    const int nkt = K / 32;
    const int tkt = DUAL ? 2 * nkt : nkt;

    float4 pv[AF4 + BF4];   // prefetch registers (~48 VGPR; total ~240 <= 256)

    auto LOADP = [&](int kt) {
        const float* Ap = A;
        const float* Wp = W;
        int kb = kt * 32;
        if (DUAL && kt >= nkt) { Ap = A2; Wp = W2; kb = (kt - nkt) * 32; }
#pragma unroll
        for (int i = 0; i < AF4; ++i) {
            const int c = tid + i * 256;
            const int row = c >> 3, k0 = (c & 7) * 4;
            pv[i] = *(const float4*)(Ap + (size_t)(m0 + row) * K + kb + k0);
        }
#pragma unroll
        for (int i = 0; i < BF4; ++i) {
            const int c = tid + i * 256;
            const int row = c >> 3, k0 = (c & 7) * 4;
            pv[AF4 + i] = *(const float4*)(Wp + (size_t)(n0 + row) * K + kb + k0);
        }
    };

    LOADP(0);

    for (int kt = 0; kt < tkt; ++kt) {
        // ---- stage prefetched regs -> LDS (split hi/lo) ----
#pragma unroll
        for (int i = 0; i < AF4; ++i) {
            const int c = tid + i * 256;
            const int row = c >> 3, k0 = (c & 7) * 4;
            cvt_store(Ah, Al, row * LDP + k0, pv[i]);
        }
#pragma unroll
        for (int i = 0; i < BF4; ++i) {
            const int c = tid + i * 256;
            const int row = c >> 3, k0 = (c & 7) * 4;
            cvt_store(Bh, Bl, row * LDP + k0, pv[AF4 + i]);
        }
        __syncthreads();

        if (kt + 1 < tkt) LOADP(kt + 1);   // issue next loads; hide under MFMA

        // ---- fragments: lane holds row (lr), k = lq*8 .. lq*8+7 ----
        bf16x8 ah[RF], al[RF];
#pragma unroll
        for (int i = 0; i < RF; ++i) {
            const int off = (wr * (BM / 2) + i * 16 + lr) * LDP + lq * 8;
            ah[i] = load_frag(Ah + off);
            al[i] = load_frag(Al + off);
        }
#pragma unroll
        for (int j = 0; j < CF; ++j) {
            const int off = (wc * (BN / 2) + j * 16 + lr) * LDP + lq * 8;
            const bf16x8 bh = load_frag(Bh + off);
            const bf16x8 bl = load_frag(Bl + off);
#pragma unroll
            for (int i = 0; i < RF; ++i) {
                acc[i][j] = __builtin_amdgcn_mfma_f32_16x16x32_bf16(ah[i], bh, acc[i][j], 0, 0, 0);
                acc[i][j] = __builtin_amdgcn_mfma_f32_16x16x32_bf16(ah[i], bl, acc[i][j], 0, 0, 0);
                acc[i][j] = __builtin_amdgcn_mfma_f32_16x16x32_bf16(al[i], bh, acc[i][j], 0, 0, 0);
            }
        }
        __syncthreads();
    }

    // ---- epilogue: C/D layout col=lane&15, row=(lane>>4)*4+reg (m89) ----
#pragma unroll
    for (int j = 0; j < CF; ++j) {
        const int col = n0 + wc * (BN / 2) + j * 16 + lr;
        float bias = b1v[col];
        if constexpr (DUAL) bias += b2v[col];
#pragma unroll
        for (int i = 0; i < RF; ++i) {
            const int rbase = m0 + wr * (BM / 2) + i * 16 + lq * 4;
#pragma unroll
            for (int r = 0; r < 4; ++r) {
                float o = acc[i][j][r] + bias;
                if (RELU) o = fmaxf(o, 0.0f);
                C[(size_t)(rbase + r) * N + col] = o;
            }
        }
    }
}

// ---------------- CSR build ----------------
__global__ __launch_bounds__(256)
void hist_kernel(const int* __restrict__ dst, int* __restrict__ cnt)
{
    const int e = blockIdx.x * 256 + threadIdx.x;   // grid covers E exactly
    atomicAdd(&cnt[dst[e]], 1);
}

// Exclusive scan of n = 1024*PT ints, single block of 1024 threads.
template<int PT>
__global__ __launch_bounds__(1024)
void scan_kernel(int* __restrict__ a)
{
    __shared__ int s[1024];
    const int t = threadIdx.x;
    int v[PT];
    int sum = 0;
#pragma unroll
    for (int k = 0; k < PT; ++k) { v[k] = a[t * PT + k]; sum += v[k]; }
    s[t] = sum;
    __syncthreads();
    for (int off = 1; off < 1024; off <<= 1) {
        int x = (t >= off) ? s[t - off] : 0;
        __syncthreads();
        s[t] += x;
        __syncthreads();
    }
    int excl = (t == 0) ? 0 : s[t - 1];
#pragma unroll
    for (int k = 0; k < PT; ++k) { int x = v[k]; a[t * PT + k] = excl; excl += x; }
}

__global__ __launch_bounds__(256)
void scatter_kernel(const int* __restrict__ dst, int* __restrict__ cursor,
                    int* __restrict__ eids)
{
    const int e = blockIdx.x * 256 + threadIdx.x;
    const int p = atomicAdd(&cursor[dst[e]], 1);
    eids[p] = e;
}
// post-scatter: cursor[d] == CSR row-end of d; row-start = cursor[d-1] (0 for d=0)

// ---------------- pull-mode aggregation: 1 wave per dst ----------------
__global__ __launch_bounds__(256)
void csr_agg_kernel(const float* __restrict__ pooled,
                    const int* __restrict__ srcA, const float* __restrict__ wA,
                    const int* __restrict__ eids, const int* __restrict__ cursor,
                    float* __restrict__ neigh, int ND)
{
    const int wid  = (blockIdx.x * 256 + threadIdx.x) >> 6;   // dst node
    const int lane = threadIdx.x & 63;
    if (wid >= ND) return;

    const int start = wid ? cursor[wid - 1] : 0;
    const int end   = cursor[wid];

    float4 m = {0.0f, 0.0f, 0.0f, 0.0f};
    for (int e = start; e < end; ++e) {
        const int   eid = eids[e];
        const int   s   = srcA[eid];
        const float ww  = wA[eid];
        const float4 p  = *(const float4*)(pooled + (size_t)s * FK + lane * 4);
        m.x = fmaxf(m.x, p.x * ww);
        m.y = fmaxf(m.y, p.y * ww);
        m.z = fmaxf(m.z, p.z * ww);
        m.w = fmaxf(m.w, p.w * ww);
    }
    *(float4*)(neigh + (size_t)wid * FK + lane * 4) = m;   // deg 0 -> zeros
}

extern "C" void kernel_launch(void* const* d_in, const int* in_sizes, int n_in,
                              void* d_out, int out_size, void* d_ws, size_t ws_size,
                              hipStream_t stream)
{
    const float* x        = (const float*)d_in[0];
    const int*   src1     = (const int*)d_in[1];
    const int*   dst1     = (const int*)d_in[2];
    const float* w1       = (const float*)d_in[3];
    const int*   src2     = (const int*)d_in[4];
    const int*   dst2     = (const int*)d_in[5];
    const float* w2       = (const float*)d_in[6];
    const float* pool_w1  = (const float*)d_in[7];
    const float* pool_b1  = (const float*)d_in[8];
    const float* self_w1  = (const float*)d_in[9];
    const float* self_b1  = (const float*)d_in[10];
    const float* neigh_w1 = (const float*)d_in[11];
    const float* neigh_b1 = (const float*)d_in[12];
    const float* pool_w2  = (const float*)d_in[13];
    const float* pool_b2  = (const float*)d_in[14];
    const float* self_w2  = (const float*)d_in[15];
    const float* self_b2  = (const float*)d_in[16];
    const float* neigh_w2 = (const float*)d_in[17];
    const float* neigh_b2 = (const float*)d_in[18];

    // ws: pooled1 [0,268.4M) dies after agg1; then h2 [0,33.5M),
    // pooled2 [33.5M,67M), neigh2 [67M,71.2M). neigh1 [268.4M,302.0M).
    // CSR: cursor1 [302.0M,+128K), eids2 [+128K,+384K), cursor2 [+384K,+400K).
    // eids1 (2MB) lives in d_out (dead before final GEMM writes output).
    char* ws = (char*)d_ws;
    float* pooled1 = (float*)ws;
    float* neigh1  = (float*)(ws + (size_t)NS1 * FK * 4);
    float* h2      = (float*)ws;
    float* pooled2 = (float*)(ws + (size_t)ND1 * FK * 4);
    float* neigh2  = (float*)(ws + (size_t)2 * ND1 * FK * 4);
    char*  csrbase = ws + (size_t)NS1 * FK * 4 + (size_t)ND1 * FK * 4;
    int*   cursor1 = (int*)csrbase;                       // 32768 ints
    int*   eids2   = (int*)(csrbase + 131072);            // 65536 ints
    int*   cursor2 = (int*)(csrbase + 131072 + 262144);   // 4096 ints
    int*   eids1   = (int*)d_out;                         // 524288 ints, exact fit
    float* out     = (float*)d_out;

    // ---- CSR builds (independent of feature data) ----
    hipMemsetAsync(cursor1, 0, ND1 * 4, stream);
    hipMemsetAsync(cursor2, 0, ND2 * 4, stream);
    hist_kernel<<<E1C / 256, 256, 0, stream>>>(dst1, cursor1);
    hist_kernel<<<E2C / 256, 256, 0, stream>>>(dst2, cursor2);
    scan_kernel<32><<<1, 1024, 0, stream>>>(cursor1);   // ND1 = 32768
    scan_kernel<4><<<1, 1024, 0, stream>>>(cursor2);    // ND2 = 4096
    scatter_kernel<<<E1C / 256, 256, 0, stream>>>(dst1, cursor1, eids1);
    scatter_kernel<<<E2C / 256, 256, 0, stream>>>(dst2, cursor2, eids2);

    // ---- L1 ----
    mfma_gemm<128, 256, true, false>
        <<<dim3(NS1 / 128, 1), 256, 0, stream>>>(
            x, pool_w1, pool_b1, nullptr, nullptr, nullptr, pooled1, NS1, FK, FK);

    csr_agg_kernel<<<ND1 / 4, 256, 0, stream>>>(pooled1, src1, w1, eids1, cursor1,
                                                neigh1, ND1);

    mfma_gemm<128, 256, true, true>
        <<<dim3(ND1 / 128, 1), 256, 0, stream>>>(
            x, self_w1, self_b1, neigh1, neigh_w1, neigh_b1, h2, ND1, FK, FK);

    // ---- L2 ----
    mfma_gemm<128, 256, true, false>
        <<<dim3(ND1 / 128, 1), 256, 0, stream>>>(
            h2, pool_w2, pool_b2, nullptr, nullptr, nullptr, pooled2, ND1, FK, FK);

    csr_agg_kernel<<<ND2 / 4, 256, 0, stream>>>(pooled2, src2, w2, eids2, cursor2,
                                                neigh2, ND2);

    mfma_gemm<64, 128, false, true>
        <<<dim3(ND2 / 64, 1), 256, 0, stream>>>(
            h2, self_w2, self_b2, neigh2, neigh_w2, neigh_b2, out, ND2, 128, FK);
}

// Round 11
// 721.328 us; speedup vs baseline: 2.0468x; 1.0665x over previous
//
#include <hip/hip_runtime.h>
#include <hip/hip_bf16.h>

// ---------------------------------------------------------------------------
// GraphSAGE 2-layer (max-pool), fp32 in/out. Split-bf16 MFMA GEMMs.
// r10 = resubmit of r6 (GPU acquisition failed 9/11 rounds; design never
// measured; three desk audits passed). vs r4 (measured 769us; pooled1 GEMM
// 168us, MfmaUtil 26 / VALU 27 / HBM 31 / Occ 20 -> stall-bound; B-staging
// = 2/3 of cvt VALU + most bank conflicts):
//  1. Weights pre-split ONCE to bf16 hi/lo (6 tiny kernels). GEMM B-tiles
//     stage via global_load_lds w=16 (async, no VALU, no write conflicts)
//     with pre-swizzled source chunks (m173) so frag ds_read_b128 at 64B row
//     stride is 2-way (free) instead of 8-way. A-side staging unchanged.
//  2. s_setprio(1) around MFMA cluster (2 blocks/CU -> phase-diverse waves).
//  3. csr_agg: 4-edge unroll -> 4 row-gathers in flight.
// Weight-split regions reuse dead zones: pool_w1 split in neigh1 space (read
// by pooled1-GEMM, clobbered by agg1 afterwards); other 5 at ws+96MB (dead
// pooled1 zone, written after agg1 consumed pooled1). Zero extra workspace.
// Audits: seg wave-uniform (gld_lds dest rule m104/m108); lane i -> base+16i
// = (row=lane>>2, slot=lane&3) matches per-lane source math; swizzle is an
// involution (write chunk cld^swz(row) at slot cld, read slot lq^swz(R));
// 16B alignment on all gld_lds sources/dests; single-buffer two-barrier
// K-step == validated m97 structure (barrier drains vmcnt before frag reads);
// DUAL half-boundary prefetch reads A2 correctly; gld_lds size arg literal.
// ---------------------------------------------------------------------------

typedef __bf16 bf16x8 __attribute__((ext_vector_type(8)));
typedef float  f32x4  __attribute__((ext_vector_type(4)));

constexpr int NS1 = 262144, ND1 = 32768, E1C = 524288, ND2 = 4096, E2C = 65536;
constexpr int FK  = 256;   // K dim everywhere
constexpr int LDP = 40;    // A-tile LDS row stride in bf16 elems (80B)

__device__ __forceinline__ void split2(float f, unsigned short& h, unsigned short& l)
{
    __bf16 hb = (__bf16)f;                    // RNE
    __bf16 lb = (__bf16)(f - (float)hb);      // residual
    h = __builtin_bit_cast(unsigned short, hb);
    l = __builtin_bit_cast(unsigned short, lb);
}

__device__ __forceinline__ void cvt_store(unsigned short* hi, unsigned short* lo,
                                          int off, float4 v)
{
    ushort4 hs, ls;
    split2(v.x, hs.x, ls.x); split2(v.y, hs.y, ls.y);
    split2(v.z, hs.z, ls.z); split2(v.w, hs.w, ls.w);
    *(ushort4*)(hi + off) = hs;
    *(ushort4*)(lo + off) = ls;
}

__device__ __forceinline__ bf16x8 load_frag(const unsigned short* p)
{
    f32x4 t = *(const f32x4*)p;               // ds_read_b128
    return __builtin_bit_cast(bf16x8, t);
}

__device__ __forceinline__ void gld_lds16(const void* g, void* l)
{
    __builtin_amdgcn_global_load_lds(
        (const __attribute__((address_space(1))) unsigned int*)g,
        (__attribute__((address_space(3))) unsigned int*)l, 16, 0, 0);
}

// ---- one-time fp32 -> (hi,lo) bf16 split of a weight matrix ----
__global__ __launch_bounds__(256)
void wsplit_kernel(const float* __restrict__ w, unsigned short* __restrict__ h,
                   unsigned short* __restrict__ l, int n4)
{
    const int i = blockIdx.x * 256 + threadIdx.x;
    if (i >= n4) return;
    const float4 v = ((const float4*)w)[i];
    ushort4 hs, ls;
    split2(v.x, hs.x, ls.x); split2(v.y, hs.y, ls.y);
    split2(v.z, hs.z, ls.z); split2(v.w, hs.w, ls.w);
    ((ushort4*)h)[i] = hs;
    ((ushort4*)l)[i] = ls;
}

// C[M][N] = act(A[M][K] @ W^T + b1 [+ A2 @ W2^T + b2]), W pre-split bf16 hi/lo.
// 256 threads = 4 waves (2x2), wave tile (BM/2)x(BN/2), 16x16x32 bf16 MFMA.
template<int BM, int BN, bool RELU, bool DUAL>
__global__ __launch_bounds__(256, 2)
void mfma_gemm2(const float* __restrict__ A,
                const unsigned short* __restrict__ Wh, const unsigned short* __restrict__ Wl,
                const float* __restrict__ b1v,
                const float* __restrict__ A2,
                const unsigned short* __restrict__ Wh2, const unsigned short* __restrict__ Wl2,
                const float* __restrict__ b2v,
                float* __restrict__ C, int M, int N, int K)
{
    constexpr int RF   = BM / 32;     // 16x16 row frags per wave
    constexpr int CF   = BN / 32;     // 16x16 col frags per wave
    constexpr int AF4  = BM / 32;     // float4 A-loads per thread per K-step
    constexpr int BSEG = BN / 64;     // gld_lds calls per wave per (h|l)
    static_assert(BM % 32 == 0 && BN % 64 == 0, "tile");

    __shared__ alignas(16) unsigned short Ah[BM * LDP], Al[BM * LDP];
    __shared__ alignas(16) unsigned short Bh[BN * 32], Bl[BN * 32];  // [row][32k] linear

    const int tid  = threadIdx.x;
    const int wid  = tid >> 6, lane = tid & 63;
    const int wr   = wid >> 1, wc = wid & 1;
    const int lq   = lane >> 4, lr = lane & 15;
    const int m0   = blockIdx.x * BM;
    const int n0   = blockIdx.y * BN;
    const int rloc = lane >> 2;       // row within 16-row segment
    const int cld  = lane & 3;        // 16B chunk slot within row

    f32x4 acc[RF][CF] = {};
    const int nkt = K / 32;
    const int tkt = DUAL ? 2 * nkt : nkt;

    float4 pv[AF4];
    auto LOADA = [&](int kt) {
        const float* Ap = A;
        int kb = kt * 32;
        if (DUAL && kt >= nkt) { Ap = A2; kb = (kt - nkt) * 32; }
#pragma unroll
        for (int i = 0; i < AF4; ++i) {
            const int c = tid + i * 256;
            const int row = c >> 3, k0 = (c & 7) * 4;
            pv[i] = *(const float4*)(Ap + (size_t)(m0 + row) * K + kb + k0);
        }
    };

    LOADA(0);

    for (int kt = 0; kt < tkt; ++kt) {
        // ---- B: async global->LDS (linear dest, swizzled SOURCE chunk; m173).
        // LDS[(row, c)] holds global chunk c ^ ((row>>1)&3) of row. ----
        {
            const unsigned short* Ph = Wh;
            const unsigned short* Pl = Wl;
            int kb = kt * 32;
            if (DUAL && kt >= nkt) { Ph = Wh2; Pl = Wl2; kb = (kt - nkt) * 32; }
#pragma unroll
            for (int c = 0; c < BSEG; ++c) {
                const int seg = wid * BSEG + c;
                const int row = seg * 16 + rloc;
                const int cg  = cld ^ ((row >> 1) & 3);
                const size_t gofs = (size_t)(n0 + row) * K + kb + cg * 8;
                gld_lds16(Ph + gofs, Bh + seg * 512);
                gld_lds16(Pl + gofs, Bl + seg * 512);
            }
        }
        // ---- A: split-cvt stage from prefetch regs (B latency hides here) ----
#pragma unroll
        for (int i = 0; i < AF4; ++i) {
            const int c = tid + i * 256;
            const int row = c >> 3, k0 = (c & 7) * 4;
            cvt_store(Ah, Al, row * LDP + k0, pv[i]);
        }
        __syncthreads();   // compiler drains vmcnt (gld_lds) + lgkmcnt here

        if (kt + 1 < tkt) LOADA(kt + 1);

        // ---- A fragments: lane = row (lr), k = lq*8..+8 ----
        bf16x8 ah[RF], al[RF];
#pragma unroll
        for (int i = 0; i < RF; ++i) {
            const int off = (wr * (BM / 2) + i * 16 + lr) * LDP + lq * 8;
            ah[i] = load_frag(Ah + off);
            al[i] = load_frag(Al + off);
        }
        __builtin_amdgcn_s_setprio(1);
#pragma unroll
        for (int j = 0; j < CF; ++j) {
            const int R   = wc * (BN / 2) + j * 16 + lr;
            const int off = R * 32 + (lq ^ ((R >> 1) & 3)) * 8;   // undo source swizzle
            const bf16x8 bh = load_frag(Bh + off);
            const bf16x8 bl = load_frag(Bl + off);
#pragma unroll
            for (int i = 0; i < RF; ++i) {
                acc[i][j] = __builtin_amdgcn_mfma_f32_16x16x32_bf16(ah[i], bh, acc[i][j], 0, 0, 0);
                acc[i][j] = __builtin_amdgcn_mfma_f32_16x16x32_bf16(ah[i], bl, acc[i][j], 0, 0, 0);
                acc[i][j] = __builtin_amdgcn_mfma_f32_16x16x32_bf16(al[i], bh, acc[i][j], 0, 0, 0);
            }
        }
        __builtin_amdgcn_s_setprio(0);
        __syncthreads();
    }

    // ---- epilogue: C/D layout col=lane&15, row=(lane>>4)*4+reg (m89) ----
#pragma unroll
    for (int j = 0; j < CF; ++j) {
        const int col = n0 + wc * (BN / 2) + j * 16 + lr;
        float bias = b1v[col];
        if constexpr (DUAL) bias += b2v[col];
#pragma unroll
        for (int i = 0; i < RF; ++i) {
            const int rbase = m0 + wr * (BM / 2) + i * 16 + lq * 4;
#pragma unroll
            for (int r = 0; r < 4; ++r) {
                float o = acc[i][j][r] + bias;
                if (RELU) o = fmaxf(o, 0.0f);
                C[(size_t)(rbase + r) * N + col] = o;
            }
        }
    }
}

// ---------------- CSR build ----------------
__global__ __launch_bounds__(256)
void hist_kernel(const int* __restrict__ dst, int* __restrict__ cnt)
{
    const int e = blockIdx.x * 256 + threadIdx.x;
    atomicAdd(&cnt[dst[e]], 1);
}

template<int PT>
__global__ __launch_bounds__(1024)
void scan_kernel(int* __restrict__ a)
{
    __shared__ int s[1024];
    const int t = threadIdx.x;
    int v[PT];
    int sum = 0;
#pragma unroll
    for (int k = 0; k < PT; ++k) { v[k] = a[t * PT + k]; sum += v[k]; }
    s[t] = sum;
    __syncthreads();
    for (int off = 1; off < 1024; off <<= 1) {
        int x = (t >= off) ? s[t - off] : 0;
        __syncthreads();
        s[t] += x;
        __syncthreads();
    }
    int excl = (t == 0) ? 0 : s[t - 1];
#pragma unroll
    for (int k = 0; k < PT; ++k) { int x = v[k]; a[t * PT + k] = excl; excl += x; }
}

__global__ __launch_bounds__(256)
void scatter_kernel(const int* __restrict__ dst, int* __restrict__ cursor,
                    int* __restrict__ eids)
{
    const int e = blockIdx.x * 256 + threadIdx.x;
    const int p = atomicAdd(&cursor[dst[e]], 1);
    eids[p] = e;
}
// post-scatter: cursor[d] == row-end of d; row-start = cursor[d-1] (0 for d=0)

// ---------------- pull-mode aggregation: 1 wave per dst, 4-edge unroll ----------------
__global__ __launch_bounds__(256)
void csr_agg_kernel(const float* __restrict__ pooled,
                    const int* __restrict__ srcA, const float* __restrict__ wA,
                    const int* __restrict__ eids, const int* __restrict__ cursor,
                    float* __restrict__ neigh, int ND)
{
    const int wid  = (blockIdx.x * 256 + threadIdx.x) >> 6;
    const int lane = threadIdx.x & 63;
    if (wid >= ND) return;

    const int start = wid ? cursor[wid - 1] : 0;
    const int end   = cursor[wid];

    float4 m = {0.0f, 0.0f, 0.0f, 0.0f};
    int e = start;
    for (; e + 3 < end; e += 4) {
        const int eid0 = eids[e], eid1 = eids[e + 1], eid2 = eids[e + 2], eid3 = eids[e + 3];
        const int s0 = srcA[eid0], s1 = srcA[eid1], s2 = srcA[eid2], s3 = srcA[eid3];
        const float w0 = wA[eid0], w1 = wA[eid1], w2 = wA[eid2], w3 = wA[eid3];
        const float4 p0 = *(const float4*)(pooled + (size_t)s0 * FK + lane * 4);
        const float4 p1 = *(const float4*)(pooled + (size_t)s1 * FK + lane * 4);
        const float4 p2 = *(const float4*)(pooled + (size_t)s2 * FK + lane * 4);
        const float4 p3 = *(const float4*)(pooled + (size_t)s3 * FK + lane * 4);
        m.x = fmaxf(fmaxf(m.x, p0.x * w0), fmaxf(p1.x * w1, fmaxf(p2.x * w2, p3.x * w3)));
        m.y = fmaxf(fmaxf(m.y, p0.y * w0), fmaxf(p1.y * w1, fmaxf(p2.y * w2, p3.y * w3)));
        m.z = fmaxf(fmaxf(m.z, p0.z * w0), fmaxf(p1.z * w1, fmaxf(p2.z * w2, p3.z * w3)));
        m.w = fmaxf(fmaxf(m.w, p0.w * w0), fmaxf(p1.w * w1, fmaxf(p2.w * w2, p3.w * w3)));
    }
    for (; e < end; ++e) {
        const int   eid = eids[e];
        const int   s   = srcA[eid];
        const float ww  = wA[eid];
        const float4 p  = *(const float4*)(pooled + (size_t)s * FK + lane * 4);
        m.x = fmaxf(m.x, p.x * ww);
        m.y = fmaxf(m.y, p.y * ww);
        m.z = fmaxf(m.z, p.z * ww);
        m.w = fmaxf(m.w, p.w * ww);
    }
    *(float4*)(neigh + (size_t)wid * FK + lane * 4) = m;   // deg 0 -> zeros
}

extern "C" void kernel_launch(void* const* d_in, const int* in_sizes, int n_in,
                              void* d_out, int out_size, void* d_ws, size_t ws_size,
                              hipStream_t stream)
{
    const float* x        = (const float*)d_in[0];
    const int*   src1     = (const int*)d_in[1];
    const int*   dst1     = (const int*)d_in[2];
    const float* w1       = (const float*)d_in[3];
    const int*   src2     = (const int*)d_in[4];
    const int*   dst2     = (const int*)d_in[5];
    const float* w2       = (const float*)d_in[6];
    const float* pool_w1  = (const float*)d_in[7];
    const float* pool_b1  = (const float*)d_in[8];
    const float* self_w1  = (const float*)d_in[9];
    const float* self_b1  = (const float*)d_in[10];
    const float* neigh_w1 = (const float*)d_in[11];
    const float* neigh_b1 = (const float*)d_in[12];
    const float* pool_w2  = (const float*)d_in[13];
    const float* pool_b2  = (const float*)d_in[14];
    const float* self_w2  = (const float*)d_in[15];
    const float* self_b2  = (const float*)d_in[16];
    const float* neigh_w2 = (const float*)d_in[17];
    const float* neigh_b2 = (const float*)d_in[18];

    // ws: pooled1 [0,268.4M) dies after agg1; then h2 [0,33.5M),
    // pooled2 [33.5M,67.1M), neigh2 [67.1M,71.3M). neigh1 [268.4M,302.0M).
    // CSR: cursor1/eids2/cursor2 after neigh1. eids1 (2MB) in d_out.
    // pool_w1 split: start of neigh1 zone (read by pooled1, clobbered by agg1).
    // other 5 splits: ws+96M (dead pooled1 zone, written after agg1).
    char* ws = (char*)d_ws;
    float* pooled1 = (float*)ws;
    float* neigh1  = (float*)(ws + (size_t)NS1 * FK * 4);
    float* h2      = (float*)ws;
    float* pooled2 = (float*)(ws + (size_t)ND1 * FK * 4);
    float* neigh2  = (float*)(ws + (size_t)2 * ND1 * FK * 4);
    char*  csrbase = ws + (size_t)NS1 * FK * 4 + (size_t)ND1 * FK * 4;
    int*   cursor1 = (int*)csrbase;                       // 32768 ints
    int*   eids2   = (int*)(csrbase + 131072);            // 65536 ints
    int*   cursor2 = (int*)(csrbase + 131072 + 262144);   // 4096 ints
    int*   eids1   = (int*)d_out;                         // 524288 ints, exact fit
    float* out     = (float*)d_out;

    unsigned short* pw1h = (unsigned short*)(ws + (size_t)NS1 * FK * 4);
    unsigned short* pw1l = pw1h + 65536;
    unsigned short* WB   = (unsigned short*)(ws + (size_t)96 * 1024 * 1024);
    unsigned short* sw1h = WB;           unsigned short* sw1l = WB + 65536;
    unsigned short* nw1h = WB + 131072;  unsigned short* nw1l = WB + 196608;
    unsigned short* pw2h = WB + 262144;  unsigned short* pw2l = WB + 327680;
    unsigned short* sw2h = WB + 393216;  unsigned short* sw2l = WB + 425984;
    unsigned short* nw2h = WB + 458752;  unsigned short* nw2l = WB + 491520;

    // ---- CSR builds ----
    hipMemsetAsync(cursor1, 0, ND1 * 4, stream);
    hipMemsetAsync(cursor2, 0, ND2 * 4, stream);
    hist_kernel<<<E1C / 256, 256, 0, stream>>>(dst1, cursor1);
    hist_kernel<<<E2C / 256, 256, 0, stream>>>(dst2, cursor2);
    scan_kernel<32><<<1, 1024, 0, stream>>>(cursor1);
    scan_kernel<4><<<1, 1024, 0, stream>>>(cursor2);
    scatter_kernel<<<E1C / 256, 256, 0, stream>>>(dst1, cursor1, eids1);
    scatter_kernel<<<E2C / 256, 256, 0, stream>>>(dst2, cursor2, eids2);

    // ---- L1 ----
    wsplit_kernel<<<64, 256, 0, stream>>>(pool_w1, pw1h, pw1l, 65536 / 4);

    mfma_gemm2<128, 256, true, false>
        <<<dim3(NS1 / 128, 1), 256, 0, stream>>>(
            x, pw1h, pw1l, pool_b1, nullptr, nullptr, nullptr, nullptr,
            pooled1, NS1, FK, FK);

    csr_agg_kernel<<<ND1 / 4, 256, 0, stream>>>(pooled1, src1, w1, eids1, cursor1,
                                                neigh1, ND1);

    // remaining weight splits (into dead pooled1 zone, after agg1 consumed it)
    wsplit_kernel<<<64, 256, 0, stream>>>(self_w1,  sw1h, sw1l, 65536 / 4);
    wsplit_kernel<<<64, 256, 0, stream>>>(neigh_w1, nw1h, nw1l, 65536 / 4);
    wsplit_kernel<<<64, 256, 0, stream>>>(pool_w2,  pw2h, pw2l, 65536 / 4);
    wsplit_kernel<<<32, 256, 0, stream>>>(self_w2,  sw2h, sw2l, 32768 / 4);
    wsplit_kernel<<<32, 256, 0, stream>>>(neigh_w2, nw2h, nw2l, 32768 / 4);

    mfma_gemm2<128, 256, true, true>
        <<<dim3(ND1 / 128, 1), 256, 0, stream>>>(
            x, sw1h, sw1l, self_b1, neigh1, nw1h, nw1l, neigh_b1,
            h2, ND1, FK, FK);

    // ---- L2 ----
    mfma_gemm2<128, 256, true, false>
        <<<dim3(ND1 / 128, 1), 256, 0, stream>>>(
            h2, pw2h, pw2l, pool_b2, nullptr, nullptr, nullptr, nullptr,
            pooled2, ND1, FK, FK);

    csr_agg_kernel<<<ND2 / 4, 256, 0, stream>>>(pooled2, src2, w2, eids2, cursor2,
                                                neigh2, ND2);

    mfma_gemm2<64, 128, false, true>
        <<<dim3(ND2 / 64, 1), 256, 0, stream>>>(
            h2, sw2h, sw2l, self_b2, neigh2, nw2h, nw2l, neigh_b2,
            out, ND2, 128, FK);
}